// Round 6
// baseline (275.865 us; speedup 1.0000x reference)
//
#include <hip/hip_runtime.h>
#include <hip/hip_bf16.h>

using bf16 = __hip_bfloat16;
typedef __attribute__((ext_vector_type(8))) short short8;
typedef __attribute__((ext_vector_type(4))) float f32x4;

static constexpr int Bc = 4, Lc = 2048, Sc = 1024;
static constexpr int DModel = 1024;

__device__ __forceinline__ void gload16(const void* g, void* l) {
  __builtin_amdgcn_global_load_lds((const __attribute__((address_space(1))) void*)g,
                                   (__attribute__((address_space(3))) void*)l,
                                   16, 0, 0);
}

__device__ __forceinline__ void wait_vm12() { asm volatile("s_waitcnt vmcnt(12)" ::: "memory"); }
__device__ __forceinline__ void wait_vm8()  { asm volatile("s_waitcnt vmcnt(8)" ::: "memory"); }
__device__ __forceinline__ void wait_vm4()  { asm volatile("s_waitcnt vmcnt(4)" ::: "memory"); }
__device__ __forceinline__ void wait_vm0()  { asm volatile("s_waitcnt vmcnt(0)" ::: "memory"); }
__device__ __forceinline__ void barrier_raw() { asm volatile("s_barrier" ::: "memory"); }

// ---------------- fused conversions ----------------
__global__ void cvt3(const float* __restrict__ a, bf16* __restrict__ ao, long na4,
                     const float* __restrict__ b, bf16* __restrict__ bo, long nb4,
                     const float* __restrict__ c, bf16* __restrict__ co, long nc4) {
  long total = na4 + nb4 + nc4;
  long stride = (long)gridDim.x * blockDim.x;
  for (long i = (long)blockIdx.x * blockDim.x + threadIdx.x; i < total; i += stride) {
    const float* src; bf16* dst; long j;
    if (i < na4)            { src = a; dst = ao; j = i; }
    else if (i < na4 + nb4) { src = b; dst = bo; j = i - na4; }
    else                    { src = c; dst = co; j = i - na4 - nb4; }
    float4 v = reinterpret_cast<const float4*>(src)[j];
    alignas(8) bf16 t[4] = {__float2bfloat16(v.x), __float2bfloat16(v.y),
                            __float2bfloat16(v.z), __float2bfloat16(v.w)};
    reinterpret_cast<ushort4*>(dst)[j] = *reinterpret_cast<const ushort4*>(t);
  }
}

// all four weight transposes (f32 [R][C] -> bf16 [C][R]) in one launch
__global__ __launch_bounds__(256) void transpose_cvt_w(const float* __restrict__ Wq, bf16* __restrict__ WqT,
                                                       const float* __restrict__ Wk, bf16* __restrict__ WkT,
                                                       const float* __restrict__ Wv, bf16* __restrict__ WvT,
                                                       const float* __restrict__ Wo, bf16* __restrict__ WoT) {
  __shared__ bf16 tile[32][33];
  int bid = blockIdx.x;
  const float* in; bf16* out; int R, l;
  if (bid < 1024)      { in = Wq; out = WqT; R = 1024; l = bid; }
  else if (bid < 5120) { in = Wk; out = WkT; R = 4096; l = bid - 1024; }
  else if (bid < 9216) { in = Wv; out = WvT; R = 4096; l = bid - 5120; }
  else                 { in = Wo; out = WoT; R = 1024; l = bid - 9216; }
  const int C = 1024;
  int bx = l & 31, by = l >> 5;
  int tx = threadIdx.x & 31, ty = threadIdx.x >> 5;
  int r0 = by * 32, c0 = bx * 32;
#pragma unroll
  for (int i = 0; i < 32; i += 8)
    tile[ty + i][tx] = __float2bfloat16(in[(long)(r0 + ty + i) * C + c0 + tx]);
  __syncthreads();
#pragma unroll
  for (int i = 0; i < 32; i += 8)
    out[(long)(c0 + ty + i) * R + r0 + tx] = tile[tx][ty + i];
}

// ============ 256x256-tile GEMM, BK=32, 8 waves, 4-deep circular LDS ============
// C[256x256 tile] = A[M][K] * Bt[N][K]^T + bias.
// LDS: 4 buffers x (A 256x32 + B 256x32) bf16 = 4 x 32KB = 128KB.
// Swizzle: row stride 64B = 4 slots of 16B; LDS slot s of row r holds source
// k-group (s ^ ((r>>1)&3)). Staged via pre-swizzled global source.
// Pipeline: prologue stages tiles 0..2; iteration t stages tile t+3 into
// buf[(t+3)&3] (freed by tile t-1's end barrier), then vmcnt(12) retires
// tile t's 4 loads (issued 3 iterations ago -> full HBM latency cover).
// NOTE: STAGE256 evaluates `buf` ONCE into _bo before its internal loop --
// R5's bug was the macro arg (t+3)&3 binding to the macro's own loop var t.
__device__ __forceinline__ void gemm256_core(const bf16* __restrict__ A, const bf16* __restrict__ Bt,
                                             const float* __restrict__ bias,
                                             bf16* __restrict__ Cb, float* __restrict__ Cf,
                                             bf16* __restrict__ Cvt,
                                             int N, int K, int bx, int by,
                                             bf16* lds) {
  const int tid = threadIdx.x;
  const int lane = tid & 63, g = lane >> 4, lm = lane & 15;
  const int wid = tid >> 6, wr = wid >> 2, wc = wid & 3;  // 2M x 4N waves
  const long brow = (long)by * 256, bcol = (long)bx * 256;

  char* Asc = (char*)lds;                    // 4 x 16KB
  char* Bsc = (char*)(lds + 4 * 8192);       // 4 x 16KB

  // staging addresses: 2 slots of 16B per matrix per thread per K-tile
  const bf16* asrc[2];
  const bf16* bsrc[2];
  int dsto[2];
#pragma unroll
  for (int t = 0; t < 2; ++t) {
    int sl = tid + t * 512;                  // 0..1023
    int row = sl >> 2;                       // 0..255
    int ks = (sl & 3) ^ ((row >> 1) & 3);    // source pre-swizzle
    asrc[t] = A + (brow + row) * (long)K + ks * 8;
    bsrc[t] = Bt + (bcol + row) * (long)K + ks * 8;
    dsto[t] = sl * 16;
  }

#define STAGE256(buf)                                        \
  {                                                          \
    const int _bo = (buf) * 16384;                           \
    _Pragma("unroll")                                        \
    for (int _t = 0; _t < 2; ++_t) {                         \
      gload16(asrc[_t], Asc + _bo + dsto[_t]);               \
      gload16(bsrc[_t], Bsc + _bo + dsto[_t]);               \
      asrc[_t] += 32; bsrc[_t] += 32;                        \
    }                                                        \
  }

  f32x4 zero = {0.f, 0.f, 0.f, 0.f};
  f32x4 acc[8][4];
#pragma unroll
  for (int i = 0; i < 8; ++i)
#pragma unroll
    for (int j = 0; j < 4; ++j) acc[i][j] = zero;

  STAGE256(0);
  STAGE256(1);
  STAGE256(2);  // 12 loads in flight

  const int nt = K >> 5;
  for (int t = 0; t < nt; ++t) {
    const int rem = nt - 1 - t;
    if (rem >= 3) { STAGE256((t + 3) & 3); wait_vm12(); }
    else if (rem == 2) wait_vm8();
    else if (rem == 1) wait_vm4();
    else               wait_vm0();
    barrier_raw();  // tile t resident for all waves

    const char* Ab = Asc + (t & 3) * 16384;
    const char* Bb = Bsc + (t & 3) * 16384;
    short8 af[8], bfv[4];
#pragma unroll
    for (int mi = 0; mi < 8; ++mi) {
      int row = wr * 128 + mi * 16 + lm;
      af[mi] = *reinterpret_cast<const short8*>(
          Ab + row * 64 + ((g ^ ((row >> 1) & 3)) << 4));
    }
#pragma unroll
    for (int ni = 0; ni < 4; ++ni) {
      int row = wc * 64 + ni * 16 + lm;
      bfv[ni] = *reinterpret_cast<const short8*>(
          Bb + row * 64 + ((g ^ ((row >> 1) & 3)) << 4));
    }
    __builtin_amdgcn_s_setprio(1);
#pragma unroll
    for (int mi = 0; mi < 8; ++mi)
#pragma unroll
      for (int ni = 0; ni < 4; ++ni)
        acc[mi][ni] = __builtin_amdgcn_mfma_f32_16x16x32_bf16(af[mi], bfv[ni], acc[mi][ni], 0, 0, 0);
    __builtin_amdgcn_s_setprio(0);
    barrier_raw();  // all waves done with buf[t&3] -> reusable at iter t+1
  }
#undef STAGE256

  // epilogue: D layout col = lane&15, row = (lane>>4)*4 + r
#pragma unroll
  for (int ni = 0; ni < 4; ++ni) {
    long n = bcol + wc * 64 + ni * 16 + lm;
    float bv = bias ? bias[n] : 0.f;
#pragma unroll
    for (int mi = 0; mi < 8; ++mi) {
      long m0 = brow + wr * 128 + mi * 16 + g * 4;
      if (Cvt) {
        long b = m0 >> 10, s0 = m0 & 1023;
        alignas(8) bf16 t4[4];
#pragma unroll
        for (int r = 0; r < 4; ++r) t4[r] = __float2bfloat16(acc[mi][ni][r] + bv);
        *reinterpret_cast<ushort4*>(Cvt + ((b << 10) + n) * 1024 + s0) =
            *reinterpret_cast<const ushort4*>(t4);
      } else {
#pragma unroll
        for (int r = 0; r < 4; ++r) {
          float o = acc[mi][ni][r] + bv;
          if (Cb) Cb[(m0 + r) * N + n] = __float2bfloat16(o);
          else    Cf[(m0 + r) * N + n] = o;
        }
      }
    }
  }
}

// QKV fused on 256^2 tiles; grid 256 = 64(K) + 64(V->vT) + 128(Q); 1 block/CU.
__global__ __launch_bounds__(512, 2) void gemm_qkv256(
    const bf16* __restrict__ Ak, const bf16* __restrict__ Bk, const float* __restrict__ bk_, bf16* __restrict__ Ck, int Kk, int nbk,
    const bf16* __restrict__ Av, const bf16* __restrict__ Bv_, const float* __restrict__ bv_, bf16* __restrict__ CvT, int Kv, int nbv,
    const bf16* __restrict__ Aq, const bf16* __restrict__ Bq_, const float* __restrict__ bq_, bf16* __restrict__ Cq, int Kq) {
  __shared__ bf16 lds[8 * 8192];  // 128 KB
  int bid = blockIdx.x;
  const bf16 *A, *Bt; const float* bias; bf16 *C = nullptr, *Cvt = nullptr; int K, l, nb;
  if (bid < nbk)            { A = Ak; Bt = Bk;  bias = bk_; C = Ck;    K = Kk; l = bid;             nb = nbk; }
  else if (bid < nbk + nbv) { A = Av; Bt = Bv_; bias = bv_; Cvt = CvT; K = Kv; l = bid - nbk;       nb = nbv; }
  else                      { A = Aq; Bt = Bq_; bias = bq_; C = Cq;   K = Kq; l = bid - nbk - nbv; nb = gridDim.x - nbk - nbv; }
  // per-segment XCD swizzle (segment sizes and offsets are multiples of 8)
  int g = (l & 7) * (nb >> 3) + (l >> 3);
  gemm256_core(A, Bt, bias, C, nullptr, Cvt, 1024, K, g & 3, g >> 2, lds);
}

// ---------------- 128^2 GEMM (2-phase dbuf, counted vmcnt) for O-proj ----------
__device__ __forceinline__ void gemm_core(const bf16* __restrict__ A, const bf16* __restrict__ Bt,
                                          const float* __restrict__ bias,
                                          bf16* __restrict__ Cb, float* __restrict__ Cf,
                                          int N, int K, int bx, int by,
                                          bf16* As, bf16* Bs) {
  const int tid = threadIdx.x;
  const int lane = tid & 63, g = lane >> 4, lm = lane & 15;
  const int wid = tid >> 6, wr = wid >> 1, wc = wid & 1;
  const long brow = (long)by * 128, bcol = (long)bx * 128;

  const bf16* asrc[4];
  const bf16* bsrc[4];
  int dsto[4];
#pragma unroll
  for (int t = 0; t < 4; ++t) {
    int sl = tid + t * 256;
    int row = sl >> 3;
    int kg = (sl & 7) ^ (row & 7);  // source pre-swizzle
    asrc[t] = A + (brow + row) * (long)K + kg * 8;
    bsrc[t] = Bt + (bcol + row) * (long)K + kg * 8;
    dsto[t] = sl * 16;
  }

  f32x4 zero = {0.f, 0.f, 0.f, 0.f};
  f32x4 acc[4][4];
#pragma unroll
  for (int i = 0; i < 4; ++i)
#pragma unroll
    for (int j = 0; j < 4; ++j) acc[i][j] = zero;

  char* Asc = (char*)As;
  char* Bsc = (char*)Bs;

#pragma unroll
  for (int t = 0; t < 4; ++t) {
    gload16(asrc[t], Asc + dsto[t]);
    gload16(bsrc[t], Bsc + dsto[t]);
    asrc[t] += 64; bsrc[t] += 64;
  }

  const int nt = K >> 6;
  for (int i = 0; i < nt; ++i) {
    const int cur = i & 1;
    if (i + 1 < nt) {
      const int nxt = cur ^ 1;
#pragma unroll
      for (int t = 0; t < 4; ++t) {
        gload16(asrc[t], Asc + nxt * 16384 + dsto[t]);
        gload16(bsrc[t], Bsc + nxt * 16384 + dsto[t]);
        asrc[t] += 64; bsrc[t] += 64;
      }
      wait_vm8();
    } else {
      wait_vm0();
    }
    barrier_raw();

    const char* Ab = Asc + cur * 16384;
    const char* Bb = Bsc + cur * 16384;
    __builtin_amdgcn_s_setprio(1);
#pragma unroll
    for (int ks = 0; ks < 2; ++ks) {
      short8 af[4], bfv[4];
#pragma unroll
      for (int mi = 0; mi < 4; ++mi) {
        int m = wr * 64 + mi * 16 + lm;
        af[mi] = *reinterpret_cast<const short8*>(
            Ab + ((m * 128 + ks * 64 + g * 16) ^ ((m & 7) << 4)));
      }
#pragma unroll
      for (int ni = 0; ni < 4; ++ni) {
        int n = wc * 64 + ni * 16 + lm;
        bfv[ni] = *reinterpret_cast<const short8*>(
            Bb + ((n * 128 + ks * 64 + g * 16) ^ ((n & 7) << 4)));
      }
#pragma unroll
      for (int mi = 0; mi < 4; ++mi)
#pragma unroll
        for (int ni = 0; ni < 4; ++ni)
          acc[mi][ni] = __builtin_amdgcn_mfma_f32_16x16x32_bf16(af[mi], bfv[ni], acc[mi][ni], 0, 0, 0);
    }
    __builtin_amdgcn_s_setprio(0);
    barrier_raw();
  }

#pragma unroll
  for (int ni = 0; ni < 4; ++ni) {
    long n = bcol + wc * 64 + ni * 16 + lm;
    float bv = bias ? bias[n] : 0.f;
#pragma unroll
    for (int mi = 0; mi < 4; ++mi) {
      long m0 = brow + wr * 64 + mi * 16 + g * 4;
#pragma unroll
      for (int r = 0; r < 4; ++r) {
        float o = acc[mi][ni][r] + bv;
        if (Cb) Cb[(m0 + r) * N + n] = __float2bfloat16(o);
        else    Cf[(m0 + r) * N + n] = o;
      }
    }
  }
}

__global__ __launch_bounds__(256) void gemm_bt(const bf16* __restrict__ A,
                                               const bf16* __restrict__ Bt,
                                               const float* __restrict__ bias,
                                               bf16* __restrict__ Cb,
                                               float* __restrict__ Cf,
                                               int N, int K) {
  __shared__ bf16 As[2 * 128 * 64];
  __shared__ bf16 Bs[2 * 128 * 64];
  int bid = blockIdx.x;
  int g = (bid & 7) * (gridDim.x >> 3) + (bid >> 3);
  gemm_core(A, Bt, bias, Cb, Cf, N, K, g & 7, g >> 3, As, Bs);
}

// ---------------- fused flash attention (2-phase, counted vmcnt, XCD swizzle) ----
__global__ __launch_bounds__(256) void attn_fused(const bf16* __restrict__ q,
                                                  const bf16* __restrict__ k,
                                                  const bf16* __restrict__ vT,
                                                  bf16* __restrict__ o) {
  constexpr float C2 = 0.18033688011112042f;  // (1/8) * log2(e)
  constexpr float THR = 6.0f;
  __shared__ bf16 Kl[2][64 * 64];
  __shared__ bf16 Vl[2][64 * 64];
  __shared__ bf16 Pl[4][16 * 64];
  const int tid = threadIdx.x;
  const int lane = tid & 63, g = lane >> 4, lm = lane & 15;
  const int wid = tid >> 6;
  int bid = blockIdx.x;
  int gl = (bid & 7) * 256 + (bid >> 3);
  const int qt = gl & 31, bh = gl >> 5;
  const int b = bh >> 4, h = bh & 15;
  const int qbase = qt * 64 + wid * 16;

  const bf16* qrow = q + (long)(b * Lc + qbase + lm) * DModel + h * 64;
  short8 qa0 = *reinterpret_cast<const short8*>(qrow + g * 8);
  short8 qa1 = *reinterpret_cast<const short8*>(qrow + 32 + g * 8);
#pragma unroll
  for (int j = 0; j < 8; ++j) {
    union { ushort u; bf16 h; } cv;
    cv.u = (ushort)qa0[j];
    bf16 s0 = __float2bfloat16(__bfloat162float(cv.h) * C2);
    qa0[j] = (short)*reinterpret_cast<ushort*>(&s0);
    cv.u = (ushort)qa1[j];
    bf16 s1 = __float2bfloat16(__bfloat162float(cv.h) * C2);
    qa1[j] = (short)*reinterpret_cast<ushort*>(&s1);
  }

  const bf16* kbase = k + (long)b * Sc * DModel + h * 64;
  const bf16* vbase = vT + ((long)b * DModel + h * 64) * Sc;

  const bf16* ksrc[2];
  const bf16* vsrc[2];
  int dsto[2];
#pragma unroll
  for (int t = 0; t < 2; ++t) {
    int sl = tid + t * 256;
    int row = sl >> 3;
    int cg = (sl & 7) ^ (row & 7);
    ksrc[t] = kbase + (long)row * DModel + cg * 8;
    vsrc[t] = vbase + (long)row * Sc + cg * 8;
    dsto[t] = sl * 16;
  }

  f32x4 zero = {0.f, 0.f, 0.f, 0.f};
  f32x4 accO[4];
#pragma unroll
  for (int i = 0; i < 4; ++i) accO[i] = zero;
  f32x4 accL = zero;
  float mst[4] = {-1e30f, -1e30f, -1e30f, -1e30f};

  short8 vones;
#pragma unroll
  for (int j = 0; j < 8; ++j) vones[j] = (short)0x3F80;  // bf16 1.0

  char* Klc = (char*)Kl;
  char* Vlc = (char*)Vl;
  char* Plc = (char*)Pl + wid * (16 * 64 * 2);

#pragma unroll
  for (int t = 0; t < 2; ++t) {
    gload16(ksrc[t], Klc + dsto[t]);
    gload16(vsrc[t], Vlc + dsto[t]);
    ksrc[t] += 64 * DModel; vsrc[t] += 64;
  }

  for (int j = 0; j < Sc / 64; ++j) {
    const int cur = j & 1;
    if (j + 1 < Sc / 64) {
      const int nxt = cur ^ 1;
#pragma unroll
      for (int t = 0; t < 2; ++t) {
        gload16(ksrc[t], Klc + nxt * 8192 + dsto[t]);
        gload16(vsrc[t], Vlc + nxt * 8192 + dsto[t]);
        ksrc[t] += 64 * DModel; vsrc[t] += 64;
      }
      wait_vm4();
    } else {
      wait_vm0();
    }
    barrier_raw();

    const char* Kb = Klc + cur * 8192;
    const char* Vb = Vlc + cur * 8192;

    f32x4 scv[4];
    __builtin_amdgcn_s_setprio(1);
#pragma unroll
    for (int st = 0; st < 4; ++st) {
      int s = st * 16 + lm;
      int sw = (s & 7) << 4;
      short8 kb0 = *reinterpret_cast<const short8*>(Kb + ((s * 128 + g * 16) ^ sw));
      short8 kb1 = *reinterpret_cast<const short8*>(Kb + ((s * 128 + 64 + g * 16) ^ sw));
      f32x4 z = zero;
      z = __builtin_amdgcn_mfma_f32_16x16x32_bf16(qa0, kb0, z, 0, 0, 0);
      z = __builtin_amdgcn_mfma_f32_16x16x32_bf16(qa1, kb1, z, 0, 0, 0);
      scv[st] = z;
    }
    __builtin_amdgcn_s_setprio(0);

    float pmax[4];
#pragma unroll
    for (int r = 0; r < 4; ++r)
      pmax[r] = fmaxf(fmaxf(scv[0][r], scv[1][r]), fmaxf(scv[2][r], scv[3][r]));
    int need = 0;
#pragma unroll
    for (int r = 0; r < 4; ++r) need |= (pmax[r] > mst[r] + THR) ? 1 : 0;
    if (__any(need)) {
#pragma unroll
      for (int r = 0; r < 4; ++r) {
        float mx = pmax[r];
        mx = fmaxf(mx, __shfl_xor(mx, 1));
        mx = fmaxf(mx, __shfl_xor(mx, 2));
        mx = fmaxf(mx, __shfl_xor(mx, 4));
        mx = fmaxf(mx, __shfl_xor(mx, 8));
        float mnew = fmaxf(mst[r], mx);
        float corr = __builtin_amdgcn_exp2f(mst[r] - mnew);
        mst[r] = mnew;
        accL[r] *= corr;
#pragma unroll
        for (int et = 0; et < 4; ++et) accO[et][r] *= corr;
      }
    }
#pragma unroll
    for (int r = 0; r < 4; ++r) {
      int qq = g * 4 + r;
      int swp = (qq & 7) << 4;
#pragma unroll
      for (int st = 0; st < 4; ++st) {
        float p = __builtin_amdgcn_exp2f(scv[st][r] - mst[r]);
        *reinterpret_cast<bf16*>(Plc + ((qq * 128 + (st * 16 + lm) * 2) ^ swp)) =
            __float2bfloat16(p);
      }
    }

    __builtin_amdgcn_s_setprio(1);
#pragma unroll
    for (int sk = 0; sk < 2; ++sk) {
      short8 pa = *reinterpret_cast<const short8*>(
          Plc + ((lm * 128 + sk * 64 + g * 16) ^ ((lm & 7) << 4)));
      accL = __builtin_amdgcn_mfma_f32_16x16x32_bf16(pa, vones, accL, 0, 0, 0);
#pragma unroll
      for (int et = 0; et < 4; ++et) {
        int e = et * 16 + lm;
        short8 vb = *reinterpret_cast<const short8*>(
            Vb + ((e * 128 + sk * 64 + g * 16) ^ ((e & 7) << 4)));
        accO[et] = __builtin_amdgcn_mfma_f32_16x16x32_bf16(pa, vb, accO[et], 0, 0, 0);
      }
    }
    __builtin_amdgcn_s_setprio(0);
    barrier_raw();
  }

#pragma unroll
  for (int r = 0; r < 4; ++r) {
    float inv = 1.0f / accL[r];
    long row = (long)(b * Lc + qbase + g * 4 + r);
#pragma unroll
    for (int et = 0; et < 4; ++et)
      o[row * DModel + h * 64 + et * 16 + lm] = __float2bfloat16(accO[et][r] * inv);
  }
}

// ---------------- host launch ----------------
extern "C" void kernel_launch(void* const* d_in, const int* in_sizes, int n_in,
                              void* d_out, int out_size, void* d_ws, size_t ws_size,
                              hipStream_t stream) {
  const float* tgt = (const float*)d_in[0];
  const float* src = (const float*)d_in[1];
  const float* val = (const float*)d_in[2];
  const float* Wq  = (const float*)d_in[3];
  const float* bq  = (const float*)d_in[4];
  const float* Wk  = (const float*)d_in[5];
  const float* bk  = (const float*)d_in[6];
  const float* Wv  = (const float*)d_in[7];
  const float* bv  = (const float*)d_in[8];
  const float* Wo  = (const float*)d_in[9];
  const float* bo  = (const float*)d_in[10];
  float* out = (float*)d_out;
  char* ws = (char*)d_ws;

  const long n4_tgt = (long)8192 * 1024 / 4;
  const long n4_sv  = (long)4096 * 4096 / 4;

  if (ws_size < (132ul << 20)) return;

  bf16* WqT  = (bf16*)(ws + (0l   << 20));  // 2 MB
  bf16* WkT  = (bf16*)(ws + (2l   << 20));  // 8 MB
  bf16* WvT  = (bf16*)(ws + (10l  << 20));  // 8 MB
  bf16* WoT  = (bf16*)(ws + (18l  << 20));  // 2 MB
  bf16* tgtb = (bf16*)(ws + (20l  << 20));  // 16 MB (attn out aliases later)
  bf16* srcb = (bf16*)(ws + (36l  << 20));  // 32 MB
  bf16* valb = (bf16*)(ws + (68l  << 20));  // 32 MB
  bf16* qb   = (bf16*)(ws + (100l << 20));  // 16 MB
  bf16* kb   = (bf16*)(ws + (116l << 20));  // 8 MB
  bf16* vTb  = (bf16*)(ws + (124l << 20));  // 8 MB [4][1024][1024] -> 132 MB
  bf16* attnb = tgtb;  // tgtb dead after QKV gemm

  transpose_cvt_w<<<10240, 256, 0, stream>>>(Wq, WqT, Wk, WkT, Wv, WvT, Wo, WoT);
  cvt3<<<4096, 256, 0, stream>>>(tgt, tgtb, n4_tgt, src, srcb, n4_sv, val, valb, n4_sv);
  // 256^2 tiles: K-proj 64 blocks, V-proj->vT 64, Q-proj 128 -> 256 = 1/CU
  gemm_qkv256<<<256, 512, 0, stream>>>(srcb, WkT, bk, kb, 4096, 64,
                                       valb, WvT, bv, vTb, 4096, 64,
                                       tgtb, WqT, bq, qb, 1024);
  attn_fused<<<2048, 256, 0, stream>>>(qb, kb, vTb, attnb);
  gemm_bt<<<512, 256, 0, stream>>>(attnb, WoT, bo, (bf16*)nullptr, out, 1024, 1024);
}

// Round 7
// 269.715 us; speedup vs baseline: 1.0228x; 1.0228x over previous
//
#include <hip/hip_runtime.h>
#include <hip/hip_bf16.h>

using bf16 = __hip_bfloat16;
typedef __attribute__((ext_vector_type(8))) short short8;
typedef __attribute__((ext_vector_type(4))) float f32x4;

static constexpr int Bc = 4, Lc = 2048, Sc = 1024;
static constexpr int DModel = 1024;

__device__ __forceinline__ void gload16(const void* g, void* l) {
  __builtin_amdgcn_global_load_lds((const __attribute__((address_space(1))) void*)g,
                                   (__attribute__((address_space(3))) void*)l,
                                   16, 0, 0);
}

__device__ __forceinline__ void wait_vm8()  { asm volatile("s_waitcnt vmcnt(8)" ::: "memory"); }
__device__ __forceinline__ void wait_vm4()  { asm volatile("s_waitcnt vmcnt(4)" ::: "memory"); }
__device__ __forceinline__ void wait_vm2()  { asm volatile("s_waitcnt vmcnt(2)" ::: "memory"); }
__device__ __forceinline__ void wait_vm0()  { asm volatile("s_waitcnt vmcnt(0)" ::: "memory"); }
__device__ __forceinline__ void barrier_raw() { asm volatile("s_barrier" ::: "memory"); }

// ---------------- fused conversions ----------------
__global__ void cvt3(const float* __restrict__ a, bf16* __restrict__ ao, long na4,
                     const float* __restrict__ b, bf16* __restrict__ bo, long nb4,
                     const float* __restrict__ c, bf16* __restrict__ co, long nc4) {
  long total = na4 + nb4 + nc4;
  long stride = (long)gridDim.x * blockDim.x;
  for (long i = (long)blockIdx.x * blockDim.x + threadIdx.x; i < total; i += stride) {
    const float* src; bf16* dst; long j;
    if (i < na4)            { src = a; dst = ao; j = i; }
    else if (i < na4 + nb4) { src = b; dst = bo; j = i - na4; }
    else                    { src = c; dst = co; j = i - na4 - nb4; }
    float4 v = reinterpret_cast<const float4*>(src)[j];
    alignas(8) bf16 t[4] = {__float2bfloat16(v.x), __float2bfloat16(v.y),
                            __float2bfloat16(v.z), __float2bfloat16(v.w)};
    reinterpret_cast<ushort4*>(dst)[j] = *reinterpret_cast<const ushort4*>(t);
  }
}

// all four weight transposes (f32 [R][C] -> bf16 [C][R]) in one launch
__global__ __launch_bounds__(256) void transpose_cvt_w(const float* __restrict__ Wq, bf16* __restrict__ WqT,
                                                       const float* __restrict__ Wk, bf16* __restrict__ WkT,
                                                       const float* __restrict__ Wv, bf16* __restrict__ WvT,
                                                       const float* __restrict__ Wo, bf16* __restrict__ WoT) {
  __shared__ bf16 tile[32][33];
  int bid = blockIdx.x;
  const float* in; bf16* out; int R, l;
  if (bid < 1024)      { in = Wq; out = WqT; R = 1024; l = bid; }
  else if (bid < 5120) { in = Wk; out = WkT; R = 4096; l = bid - 1024; }
  else if (bid < 9216) { in = Wv; out = WvT; R = 4096; l = bid - 5120; }
  else                 { in = Wo; out = WoT; R = 1024; l = bid - 9216; }
  const int C = 1024;
  int bx = l & 31, by = l >> 5;
  int tx = threadIdx.x & 31, ty = threadIdx.x >> 5;
  int r0 = by * 32, c0 = bx * 32;
#pragma unroll
  for (int i = 0; i < 32; i += 8)
    tile[ty + i][tx] = __float2bfloat16(in[(long)(r0 + ty + i) * C + c0 + tx]);
  __syncthreads();
#pragma unroll
  for (int i = 0; i < 32; i += 8)
    out[(long)(c0 + ty + i) * R + r0 + tx] = tile[tx][ty + i];
}

// ============ 256x256-tile 8-phase GEMM (m201-style), BK=64, 8 waves ============
// C[256x256] = A[M][K] * Bt[N][K]^T + bias.
// LDS: A/B each 2dbuf x 2half x (128 rows x 64 cols bf16 = 16KB) = 64KB -> 128KB.
// Half-tile rows are 128B (8 slots of 16B); slot s of row r holds source k-group
// (s ^ (r&7)) -- staged via pre-swizzled global source, read via same XOR.
// K-tile t (BK=64) lives in buf t&1. 4 phases per tile, one C-quadrant each:
//   p1 q=(0,0): LDA(h0) LDB(h0) | stage A0(t+1) | bar | 16 MFMA | vm4 | bar
//   p2 q=(0,1):        LDB(h1)  | stage B0(t+1) | bar | 16 MFMA | vm4 | bar
//   p3 q=(1,1): LDA(h1)         | stage B1(t+1) | bar | 16 MFMA |     | bar
//   p4 q=(1,0):        LDB(h0)  | stage A1(t+1) | bar | 16 MFMA | vm4 | bar
// vmcnt FIFO accounting (2 loads per stage, in-order retirement):
//   end p1: outstanding {B1(t),A1(t),A0(t+1)}=6 -> vm4 retires B1(t)  (read @p2)
//   end p2: outstanding {A1(t),A0(t+1),B0(t+1)}=6 -> vm4 retires A1(t) (read @p3)
//   end p4: outstanding {A0,B0,B1,A1}(t+1)=8 -> vm4 retires A0,B0(t+1) (read @p1)
// Every half-tile has >=3 phases of issue->consume cover; waits never drain to 0
// in steady state. Last tile (no staging): vm2 / vm0 / none / none.
__device__ __forceinline__ void gemm8p_core(const bf16* __restrict__ A, const bf16* __restrict__ Bt,
                                            const float* __restrict__ bias,
                                            bf16* __restrict__ Cb, float* __restrict__ Cf,
                                            bf16* __restrict__ Cvt,
                                            int N, int K, int bx, int by,
                                            bf16* lds) {
  const int tid = threadIdx.x;
  const int lane = tid & 63, g = lane >> 4, lm = lane & 15;
  const int wid = tid >> 6, wr = wid >> 2, wc = wid & 3;  // 2M x 4N waves
  const long brow = (long)by * 256, bcol = (long)bx * 256;

  char* Al = (char*)lds;            // 4 x 16KB: (buf*2+half)*16384
  char* Bl = (char*)lds + 65536;    // 4 x 16KB

  // staging: thread covers slots tid and tid+512 of each half-tile (1024 slots)
  const int row0 = tid >> 3,          kg0 = (tid & 7) ^ (row0 & 7);
  const int row1 = (tid + 512) >> 3,  kg1 = ((tid + 512) & 7) ^ (row1 & 7);
  const int d0 = tid * 16, d1 = (tid + 512) * 16;
  const bf16* aS0 = A + (brow + row0) * (long)K + kg0 * 8;
  const bf16* aS1 = A + (brow + row1) * (long)K + kg1 * 8;
  const bf16* bS0 = Bt + (bcol + row0) * (long)K + kg0 * 8;
  const bf16* bS1 = Bt + (bcol + row1) * (long)K + kg1 * 8;
  const long hK = 128l * K;

#define STAGE_A(t_, h_) { const long so_ = (long)(h_) * hK + (long)(t_) * 64;  \
    const int bo_ = (((t_) & 1) * 2 + (h_)) * 16384;                            \
    gload16(aS0 + so_, Al + bo_ + d0); gload16(aS1 + so_, Al + bo_ + d1); }
#define STAGE_B(t_, h_) { const long so_ = (long)(h_) * hK + (long)(t_) * 64;  \
    const int bo_ = (((t_) & 1) * 2 + (h_)) * 16384;                            \
    gload16(bS0 + so_, Bl + bo_ + d0); gload16(bS1 + so_, Bl + bo_ + d1); }

#define LDA(qm_)                                                                \
  _Pragma("unroll") for (int mi = 0; mi < 4; ++mi)                              \
  _Pragma("unroll") for (int ks = 0; ks < 2; ++ks) {                            \
    const int r_ = wr * 64 + mi * 16 + lm;                                      \
    aR[mi][ks] = *reinterpret_cast<const short8*>(                              \
        Al + (buf * 2 + (qm_)) * 16384 + r_ * 128 +                             \
        ((((ks << 2) + g) ^ (r_ & 7)) << 4)); }
#define LDB(qn_)                                                                \
  _Pragma("unroll") for (int ni = 0; ni < 2; ++ni)                              \
  _Pragma("unroll") for (int ks = 0; ks < 2; ++ks) {                            \
    const int r_ = wc * 32 + ni * 16 + lm;                                      \
    bR[ni][ks] = *reinterpret_cast<const short8*>(                              \
        Bl + (buf * 2 + (qn_)) * 16384 + r_ * 128 +                             \
        ((((ks << 2) + g) ^ (r_ & 7)) << 4)); }
#define PHASE_MFMA(f_)                                                          \
  __builtin_amdgcn_s_setprio(1);                                                \
  _Pragma("unroll") for (int mi = 0; mi < 4; ++mi)                              \
  _Pragma("unroll") for (int ni = 0; ni < 2; ++ni)                              \
  _Pragma("unroll") for (int ks = 0; ks < 2; ++ks)                              \
    acc[f_][mi][ni] = __builtin_amdgcn_mfma_f32_16x16x32_bf16(                  \
        aR[mi][ks], bR[ni][ks], acc[f_][mi][ni], 0, 0, 0);                      \
  __builtin_amdgcn_s_setprio(0);

  f32x4 zero = {0.f, 0.f, 0.f, 0.f};
  f32x4 acc[4][4][2];
#pragma unroll
  for (int f = 0; f < 4; ++f)
#pragma unroll
    for (int i = 0; i < 4; ++i)
#pragma unroll
      for (int j = 0; j < 2; ++j) acc[f][i][j] = zero;

  short8 aR[4][2], bR[2][2];

  // prologue: stage tile 0 (issue order A0,B0,B1,A1); certify A0,B0
  STAGE_A(0, 0); STAGE_B(0, 0); STAGE_B(0, 1); STAGE_A(0, 1);
  wait_vm4();
  barrier_raw();

  const int nt = K >> 6;
  for (int t = 0; t < nt; ++t) {
    const int buf = t & 1;
    const bool more = (t + 1 < nt);
    // ---- phase 1: quadrant (0,0)
    LDA(0); LDB(0);
    if (more) STAGE_A(t + 1, 0);
    barrier_raw();
    PHASE_MFMA(0);
    if (more) wait_vm4(); else wait_vm2();
    barrier_raw();
    // ---- phase 2: quadrant (0,1) -- reuse aR
    LDB(1);
    if (more) STAGE_B(t + 1, 0);
    barrier_raw();
    PHASE_MFMA(1);
    if (more) wait_vm4(); else wait_vm0();
    barrier_raw();
    // ---- phase 3: quadrant (1,1) -- reuse bR
    LDA(1);
    if (more) STAGE_B(t + 1, 1);
    barrier_raw();
    PHASE_MFMA(2);
    barrier_raw();
    // ---- phase 4: quadrant (1,0) -- reuse aR
    LDB(0);
    if (more) STAGE_A(t + 1, 1);
    barrier_raw();
    PHASE_MFMA(3);
    if (more) wait_vm4();
    barrier_raw();
  }
#undef STAGE_A
#undef STAGE_B
#undef LDA
#undef LDB
#undef PHASE_MFMA

  // epilogue: quadrant f -> (qm,qn); D layout col = lane&15, row = (lane>>4)*4+r
  const int QMv[4] = {0, 0, 1, 1}, QNv[4] = {0, 1, 1, 0};
#pragma unroll
  for (int f = 0; f < 4; ++f) {
    const int qm = QMv[f], qn = QNv[f];
#pragma unroll
    for (int ni = 0; ni < 2; ++ni) {
      long n = bcol + qn * 128 + wc * 32 + ni * 16 + lm;
      float bv = bias ? bias[n] : 0.f;
#pragma unroll
      for (int mi = 0; mi < 4; ++mi) {
        long m0 = brow + qm * 128 + wr * 64 + mi * 16 + g * 4;
        if (Cvt) {
          long b = m0 >> 10, s0 = m0 & 1023;
          alignas(8) bf16 t4[4];
#pragma unroll
          for (int r = 0; r < 4; ++r) t4[r] = __float2bfloat16(acc[f][mi][ni][r] + bv);
          *reinterpret_cast<ushort4*>(Cvt + ((b << 10) + n) * 1024 + s0) =
              *reinterpret_cast<const ushort4*>(t4);
        } else {
#pragma unroll
          for (int r = 0; r < 4; ++r) {
            float o = acc[f][mi][ni][r] + bv;
            if (Cb) Cb[(m0 + r) * N + n] = __float2bfloat16(o);
            else    Cf[(m0 + r) * N + n] = o;
          }
        }
      }
    }
  }
}

// QKV fused on 256^2 8-phase tiles; grid 256 = 64(K) + 64(V->vT) + 128(Q).
__global__ __launch_bounds__(512, 2) void gemm_qkv8p(
    const bf16* __restrict__ Ak, const bf16* __restrict__ Bk, const float* __restrict__ bk_, bf16* __restrict__ Ck, int Kk, int nbk,
    const bf16* __restrict__ Av, const bf16* __restrict__ Bv_, const float* __restrict__ bv_, bf16* __restrict__ CvT, int Kv, int nbv,
    const bf16* __restrict__ Aq, const bf16* __restrict__ Bq_, const float* __restrict__ bq_, bf16* __restrict__ Cq, int Kq) {
  __shared__ bf16 lds[65536];  // 128 KB
  int bid = blockIdx.x;
  const bf16 *A, *Bt; const float* bias; bf16 *C = nullptr, *Cvt = nullptr; int K, l, nb;
  if (bid < nbk)            { A = Ak; Bt = Bk;  bias = bk_; C = Ck;    K = Kk; l = bid;             nb = nbk; }
  else if (bid < nbk + nbv) { A = Av; Bt = Bv_; bias = bv_; Cvt = CvT; K = Kv; l = bid - nbk;       nb = nbv; }
  else                      { A = Aq; Bt = Bq_; bias = bq_; C = Cq;   K = Kq; l = bid - nbk - nbv; nb = gridDim.x - nbk - nbv; }
  // per-segment XCD swizzle (segment sizes and offsets are multiples of 8)
  int g = (l & 7) * (nb >> 3) + (l >> 3);
  gemm8p_core(A, Bt, bias, C, nullptr, Cvt, 1024, K, g & 3, g >> 2, lds);
}

// ---------------- 128^2 GEMM (2-phase dbuf, counted vmcnt) for O-proj ----------
__device__ __forceinline__ void gemm_core(const bf16* __restrict__ A, const bf16* __restrict__ Bt,
                                          const float* __restrict__ bias,
                                          bf16* __restrict__ Cb, float* __restrict__ Cf,
                                          int N, int K, int bx, int by,
                                          bf16* As, bf16* Bs) {
  const int tid = threadIdx.x;
  const int lane = tid & 63, g = lane >> 4, lm = lane & 15;
  const int wid = tid >> 6, wr = wid >> 1, wc = wid & 1;
  const long brow = (long)by * 128, bcol = (long)bx * 128;

  const bf16* asrc[4];
  const bf16* bsrc[4];
  int dsto[4];
#pragma unroll
  for (int t = 0; t < 4; ++t) {
    int sl = tid + t * 256;
    int row = sl >> 3;
    int kg = (sl & 7) ^ (row & 7);  // source pre-swizzle
    asrc[t] = A + (brow + row) * (long)K + kg * 8;
    bsrc[t] = Bt + (bcol + row) * (long)K + kg * 8;
    dsto[t] = sl * 16;
  }

  f32x4 zero = {0.f, 0.f, 0.f, 0.f};
  f32x4 acc[4][4];
#pragma unroll
  for (int i = 0; i < 4; ++i)
#pragma unroll
    for (int j = 0; j < 4; ++j) acc[i][j] = zero;

  char* Asc = (char*)As;
  char* Bsc = (char*)Bs;

#pragma unroll
  for (int t = 0; t < 4; ++t) {
    gload16(asrc[t], Asc + dsto[t]);
    gload16(bsrc[t], Bsc + dsto[t]);
    asrc[t] += 64; bsrc[t] += 64;
  }

  const int nt = K >> 6;
  for (int i = 0; i < nt; ++i) {
    const int cur = i & 1;
    if (i + 1 < nt) {
      const int nxt = cur ^ 1;
#pragma unroll
      for (int t = 0; t < 4; ++t) {
        gload16(asrc[t], Asc + nxt * 16384 + dsto[t]);
        gload16(bsrc[t], Bsc + nxt * 16384 + dsto[t]);
        asrc[t] += 64; bsrc[t] += 64;
      }
      wait_vm8();
    } else {
      wait_vm0();
    }
    barrier_raw();

    const char* Ab = Asc + cur * 16384;
    const char* Bb = Bsc + cur * 16384;
    __builtin_amdgcn_s_setprio(1);
#pragma unroll
    for (int ks = 0; ks < 2; ++ks) {
      short8 af[4], bfv[4];
#pragma unroll
      for (int mi = 0; mi < 4; ++mi) {
        int m = wr * 64 + mi * 16 + lm;
        af[mi] = *reinterpret_cast<const short8*>(
            Ab + ((m * 128 + ks * 64 + g * 16) ^ ((m & 7) << 4)));
      }
#pragma unroll
      for (int ni = 0; ni < 4; ++ni) {
        int n = wc * 64 + ni * 16 + lm;
        bfv[ni] = *reinterpret_cast<const short8*>(
            Bb + ((n * 128 + ks * 64 + g * 16) ^ ((n & 7) << 4)));
      }
#pragma unroll
      for (int mi = 0; mi < 4; ++mi)
#pragma unroll
        for (int ni = 0; ni < 4; ++ni)
          acc[mi][ni] = __builtin_amdgcn_mfma_f32_16x16x32_bf16(af[mi], bfv[ni], acc[mi][ni], 0, 0, 0);
    }
    __builtin_amdgcn_s_setprio(0);
    barrier_raw();
  }

#pragma unroll
  for (int ni = 0; ni < 4; ++ni) {
    long n = bcol + wc * 64 + ni * 16 + lm;
    float bv = bias ? bias[n] : 0.f;
#pragma unroll
    for (int mi = 0; mi < 4; ++mi) {
      long m0 = brow + wr * 64 + mi * 16 + g * 4;
#pragma unroll
      for (int r = 0; r < 4; ++r) {
        float o = acc[mi][ni][r] + bv;
        if (Cb) Cb[(m0 + r) * N + n] = __float2bfloat16(o);
        else    Cf[(m0 + r) * N + n] = o;
      }
    }
  }
}

__global__ __launch_bounds__(256) void gemm_bt(const bf16* __restrict__ A,
                                               const bf16* __restrict__ Bt,
                                               const float* __restrict__ bias,
                                               bf16* __restrict__ Cb,
                                               float* __restrict__ Cf,
                                               int N, int K) {
  __shared__ bf16 As[2 * 128 * 64];
  __shared__ bf16 Bs[2 * 128 * 64];
  int bid = blockIdx.x;
  int g = (bid & 7) * (gridDim.x >> 3) + (bid >> 3);
  gemm_core(A, Bt, bias, Cb, Cf, N, K, g & 7, g >> 3, As, Bs);
}

// ---------------- fused flash attention (2-phase, counted vmcnt, XCD swizzle) ----
__global__ __launch_bounds__(256) void attn_fused(const bf16* __restrict__ q,
                                                  const bf16* __restrict__ k,
                                                  const bf16* __restrict__ vT,
                                                  bf16* __restrict__ o) {
  constexpr float C2 = 0.18033688011112042f;  // (1/8) * log2(e)
  constexpr float THR = 6.0f;
  __shared__ bf16 Kl[2][64 * 64];
  __shared__ bf16 Vl[2][64 * 64];
  __shared__ bf16 Pl[4][16 * 64];
  const int tid = threadIdx.x;
  const int lane = tid & 63, g = lane >> 4, lm = lane & 15;
  const int wid = tid >> 6;
  int bid = blockIdx.x;
  int gl = (bid & 7) * 256 + (bid >> 3);
  const int qt = gl & 31, bh = gl >> 5;
  const int b = bh >> 4, h = bh & 15;
  const int qbase = qt * 64 + wid * 16;

  const bf16* qrow = q + (long)(b * Lc + qbase + lm) * DModel + h * 64;
  short8 qa0 = *reinterpret_cast<const short8*>(qrow + g * 8);
  short8 qa1 = *reinterpret_cast<const short8*>(qrow + 32 + g * 8);
#pragma unroll
  for (int j = 0; j < 8; ++j) {
    union { ushort u; bf16 h; } cv;
    cv.u = (ushort)qa0[j];
    bf16 s0 = __float2bfloat16(__bfloat162float(cv.h) * C2);
    qa0[j] = (short)*reinterpret_cast<ushort*>(&s0);
    cv.u = (ushort)qa1[j];
    bf16 s1 = __float2bfloat16(__bfloat162float(cv.h) * C2);
    qa1[j] = (short)*reinterpret_cast<ushort*>(&s1);
  }

  const bf16* kbase = k + (long)b * Sc * DModel + h * 64;
  const bf16* vbase = vT + ((long)b * DModel + h * 64) * Sc;

  const bf16* ksrc[2];
  const bf16* vsrc[2];
  int dsto[2];
#pragma unroll
  for (int t = 0; t < 2; ++t) {
    int sl = tid + t * 256;
    int row = sl >> 3;
    int cg = (sl & 7) ^ (row & 7);
    ksrc[t] = kbase + (long)row * DModel + cg * 8;
    vsrc[t] = vbase + (long)row * Sc + cg * 8;
    dsto[t] = sl * 16;
  }

  f32x4 zero = {0.f, 0.f, 0.f, 0.f};
  f32x4 accO[4];
#pragma unroll
  for (int i = 0; i < 4; ++i) accO[i] = zero;
  f32x4 accL = zero;
  float mst[4] = {-1e30f, -1e30f, -1e30f, -1e30f};

  short8 vones;
#pragma unroll
  for (int j = 0; j < 8; ++j) vones[j] = (short)0x3F80;  // bf16 1.0

  char* Klc = (char*)Kl;
  char* Vlc = (char*)Vl;
  char* Plc = (char*)Pl + wid * (16 * 64 * 2);

#pragma unroll
  for (int t = 0; t < 2; ++t) {
    gload16(ksrc[t], Klc + dsto[t]);
    gload16(vsrc[t], Vlc + dsto[t]);
    ksrc[t] += 64 * DModel; vsrc[t] += 64;
  }

  for (int j = 0; j < Sc / 64; ++j) {
    const int cur = j & 1;
    if (j + 1 < Sc / 64) {
      const int nxt = cur ^ 1;
#pragma unroll
      for (int t = 0; t < 2; ++t) {
        gload16(ksrc[t], Klc + nxt * 8192 + dsto[t]);
        gload16(vsrc[t], Vlc + nxt * 8192 + dsto[t]);
        ksrc[t] += 64 * DModel; vsrc[t] += 64;
      }
      wait_vm4();
    } else {
      wait_vm0();
    }
    barrier_raw();

    const char* Kb = Klc + cur * 8192;
    const char* Vb = Vlc + cur * 8192;

    f32x4 scv[4];
    __builtin_amdgcn_s_setprio(1);
#pragma unroll
    for (int st = 0; st < 4; ++st) {
      int s = st * 16 + lm;
      int sw = (s & 7) << 4;
      short8 kb0 = *reinterpret_cast<const short8*>(Kb + ((s * 128 + g * 16) ^ sw));
      short8 kb1 = *reinterpret_cast<const short8*>(Kb + ((s * 128 + 64 + g * 16) ^ sw));
      f32x4 z = zero;
      z = __builtin_amdgcn_mfma_f32_16x16x32_bf16(qa0, kb0, z, 0, 0, 0);
      z = __builtin_amdgcn_mfma_f32_16x16x32_bf16(qa1, kb1, z, 0, 0, 0);
      scv[st] = z;
    }
    __builtin_amdgcn_s_setprio(0);

    float pmax[4];
#pragma unroll
    for (int r = 0; r < 4; ++r)
      pmax[r] = fmaxf(fmaxf(scv[0][r], scv[1][r]), fmaxf(scv[2][r], scv[3][r]));
    int need = 0;
#pragma unroll
    for (int r = 0; r < 4; ++r) need |= (pmax[r] > mst[r] + THR) ? 1 : 0;
    if (__any(need)) {
#pragma unroll
      for (int r = 0; r < 4; ++r) {
        float mx = pmax[r];
        mx = fmaxf(mx, __shfl_xor(mx, 1));
        mx = fmaxf(mx, __shfl_xor(mx, 2));
        mx = fmaxf(mx, __shfl_xor(mx, 4));
        mx = fmaxf(mx, __shfl_xor(mx, 8));
        float mnew = fmaxf(mst[r], mx);
        float corr = __builtin_amdgcn_exp2f(mst[r] - mnew);
        mst[r] = mnew;
        accL[r] *= corr;
#pragma unroll
        for (int et = 0; et < 4; ++et) accO[et][r] *= corr;
      }
    }
#pragma unroll
    for (int r = 0; r < 4; ++r) {
      int qq = g * 4 + r;
      int swp = (qq & 7) << 4;
#pragma unroll
      for (int st = 0; st < 4; ++st) {
        float p = __builtin_amdgcn_exp2f(scv[st][r] - mst[r]);
        *reinterpret_cast<bf16*>(Plc + ((qq * 128 + (st * 16 + lm) * 2) ^ swp)) =
            __float2bfloat16(p);
      }
    }

    __builtin_amdgcn_s_setprio(1);
#pragma unroll
    for (int sk = 0; sk < 2; ++sk) {
      short8 pa = *reinterpret_cast<const short8*>(
          Plc + ((lm * 128 + sk * 64 + g * 16) ^ ((lm & 7) << 4)));
      accL = __builtin_amdgcn_mfma_f32_16x16x32_bf16(pa, vones, accL, 0, 0, 0);
#pragma unroll
      for (int et = 0; et < 4; ++et) {
        int e = et * 16 + lm;
        short8 vb = *reinterpret_cast<const short8*>(
            Vb + ((e * 128 + sk * 64 + g * 16) ^ ((e & 7) << 4)));
        accO[et] = __builtin_amdgcn_mfma_f32_16x16x32_bf16(pa, vb, accO[et], 0, 0, 0);
      }
    }
    __builtin_amdgcn_s_setprio(0);
    barrier_raw();
  }

#pragma unroll
  for (int r = 0; r < 4; ++r) {
    float inv = 1.0f / accL[r];
    long row = (long)(b * Lc + qbase + g * 4 + r);
#pragma unroll
    for (int et = 0; et < 4; ++et)
      o[row * DModel + h * 64 + et * 16 + lm] = __float2bfloat16(accO[et][r] * inv);
  }
}

// ---------------- host launch ----------------
extern "C" void kernel_launch(void* const* d_in, const int* in_sizes, int n_in,
                              void* d_out, int out_size, void* d_ws, size_t ws_size,
                              hipStream_t stream) {
  const float* tgt = (const float*)d_in[0];
  const float* src = (const float*)d_in[1];
  const float* val = (const float*)d_in[2];
  const float* Wq  = (const float*)d_in[3];
  const float* bq  = (const float*)d_in[4];
  const float* Wk  = (const float*)d_in[5];
  const float* bk  = (const float*)d_in[6];
  const float* Wv  = (const float*)d_in[7];
  const float* bv  = (const float*)d_in[8];
  const float* Wo  = (const float*)d_in[9];
  const float* bo  = (const float*)d_in[10];
  float* out = (float*)d_out;
  char* ws = (char*)d_ws;

  const long n4_tgt = (long)8192 * 1024 / 4;
  const long n4_sv  = (long)4096 * 4096 / 4;

  if (ws_size < (132ul << 20)) return;

  bf16* WqT  = (bf16*)(ws + (0l   << 20));  // 2 MB
  bf16* WkT  = (bf16*)(ws + (2l   << 20));  // 8 MB
  bf16* WvT  = (bf16*)(ws + (10l  << 20));  // 8 MB
  bf16* WoT  = (bf16*)(ws + (18l  << 20));  // 2 MB
  bf16* tgtb = (bf16*)(ws + (20l  << 20));  // 16 MB (attn out aliases later)
  bf16* srcb = (bf16*)(ws + (36l  << 20));  // 32 MB
  bf16* valb = (bf16*)(ws + (68l  << 20));  // 32 MB
  bf16* qb   = (bf16*)(ws + (100l << 20));  // 16 MB
  bf16* kb   = (bf16*)(ws + (116l << 20));  // 8 MB
  bf16* vTb  = (bf16*)(ws + (124l << 20));  // 8 MB [4][1024][1024] -> 132 MB
  bf16* attnb = tgtb;  // tgtb dead after QKV gemm

  transpose_cvt_w<<<10240, 256, 0, stream>>>(Wq, WqT, Wk, WkT, Wv, WvT, Wo, WoT);
  cvt3<<<4096, 256, 0, stream>>>(tgt, tgtb, n4_tgt, src, srcb, n4_sv, val, valb, n4_sv);
  // 256^2 8-phase tiles: K-proj 64 blocks, V-proj->vT 64, Q-proj 128 -> 256 = 1/CU
  gemm_qkv8p<<<256, 512, 0, stream>>>(srcb, WkT, bk, kb, 4096, 64,
                                      valb, WvT, bv, vTb, 4096, 64,
                                      tgtb, WqT, bq, qb, 1024);
  attn_fused<<<2048, 256, 0, stream>>>(qb, kb, vTb, attnb);
  gemm_bt<<<512, 256, 0, stream>>>(attnb, WoT, bo, (bf16*)nullptr, out, 1024, 1024);
}

// Round 8
// 242.773 us; speedup vs baseline: 1.1363x; 1.1110x over previous
//
#include <hip/hip_runtime.h>
#include <hip/hip_bf16.h>

using bf16 = __hip_bfloat16;
typedef __attribute__((ext_vector_type(8))) short short8;
typedef __attribute__((ext_vector_type(4))) float f32x4;

static constexpr int Bc = 4, Lc = 2048, Sc = 1024;
static constexpr int DModel = 1024;

__device__ __forceinline__ void gload16(const void* g, void* l) {
  __builtin_amdgcn_global_load_lds((const __attribute__((address_space(1))) void*)g,
                                   (__attribute__((address_space(3))) void*)l,
                                   16, 0, 0);
}

__device__ __forceinline__ void wait_vm8()  { asm volatile("s_waitcnt vmcnt(8)" ::: "memory"); }
__device__ __forceinline__ void wait_vm6()  { asm volatile("s_waitcnt vmcnt(6)" ::: "memory"); }
__device__ __forceinline__ void wait_vm4()  { asm volatile("s_waitcnt vmcnt(4)" ::: "memory"); }
__device__ __forceinline__ void wait_vm3()  { asm volatile("s_waitcnt vmcnt(3)" ::: "memory"); }
__device__ __forceinline__ void wait_vm0()  { asm volatile("s_waitcnt vmcnt(0)" ::: "memory"); }
__device__ __forceinline__ void barrier_raw() { asm volatile("s_barrier" ::: "memory"); }

// ---------------- fused conversions ----------------
__global__ void cvt3(const float* __restrict__ a, bf16* __restrict__ ao, long na4,
                     const float* __restrict__ b, bf16* __restrict__ bo, long nb4,
                     const float* __restrict__ c, bf16* __restrict__ co, long nc4) {
  long total = na4 + nb4 + nc4;
  long stride = (long)gridDim.x * blockDim.x;
  for (long i = (long)blockIdx.x * blockDim.x + threadIdx.x; i < total; i += stride) {
    const float* src; bf16* dst; long j;
    if (i < na4)            { src = a; dst = ao; j = i; }
    else if (i < na4 + nb4) { src = b; dst = bo; j = i - na4; }
    else                    { src = c; dst = co; j = i - na4 - nb4; }
    float4 v = reinterpret_cast<const float4*>(src)[j];
    alignas(8) bf16 t[4] = {__float2bfloat16(v.x), __float2bfloat16(v.y),
                            __float2bfloat16(v.z), __float2bfloat16(v.w)};
    reinterpret_cast<ushort4*>(dst)[j] = *reinterpret_cast<const ushort4*>(t);
  }
}

// all four weight transposes (f32 [R][C] -> bf16 [C][R]) in one launch
__global__ __launch_bounds__(256) void transpose_cvt_w(const float* __restrict__ Wq, bf16* __restrict__ WqT,
                                                       const float* __restrict__ Wk, bf16* __restrict__ WkT,
                                                       const float* __restrict__ Wv, bf16* __restrict__ WvT,
                                                       const float* __restrict__ Wo, bf16* __restrict__ WoT) {
  __shared__ bf16 tile[32][33];
  int bid = blockIdx.x;
  const float* in; bf16* out; int R, l;
  if (bid < 1024)      { in = Wq; out = WqT; R = 1024; l = bid; }
  else if (bid < 5120) { in = Wk; out = WkT; R = 4096; l = bid - 1024; }
  else if (bid < 9216) { in = Wv; out = WvT; R = 4096; l = bid - 5120; }
  else                 { in = Wo; out = WoT; R = 1024; l = bid - 9216; }
  const int C = 1024;
  int bx = l & 31, by = l >> 5;
  int tx = threadIdx.x & 31, ty = threadIdx.x >> 5;
  int r0 = by * 32, c0 = bx * 32;
#pragma unroll
  for (int i = 0; i < 32; i += 8)
    tile[ty + i][tx] = __float2bfloat16(in[(long)(r0 + ty + i) * C + c0 + tx]);
  __syncthreads();
#pragma unroll
  for (int i = 0; i < 32; i += 8)
    out[(long)(c0 + ty + i) * R + r0 + tx] = tile[tx][ty + i];
}

// ======== balanced QKV GEMM: 256x128 tile, BK=32, 8 waves, 3-deep LDS ========
// C[256x128] = A[M][K] * Bt[N][K]^T + bias  (N = 1024 fixed).
// LDS: 3 rotating buffers x (A 256x32 = 16KB + B 128x32 = 8KB) = 72KB.
//   -> 2 blocks/CU (144KB LDS); __launch_bounds__(512,4) keeps VGPR <= 128 so
//      16 waves/CU (4/SIMD) fit: cross-block overlap hides staging latency.
// Rows are 64B = 4 slots of 16B; slot s of row r holds source k-group
// s ^ ((r>>1)&3) (2-way bank aliasing = free), staged via pre-swizzled source.
// Pipeline: stage tiles 0,1; iter t stages t+2 into buf (t+2)%3 (freed by
// iter t-1's end barrier), waits vmcnt(6) -> certifies tile t (issued 2 iters
// ago, ~2 compute-phases of latency cover). 3 loads/thread per stage.
__device__ __forceinline__ void gemm_bal_core(const bf16* __restrict__ A, const bf16* __restrict__ Bt,
                                              const float* __restrict__ bias,
                                              bf16* __restrict__ Cb, bf16* __restrict__ Cvt,
                                              int K, int bx, int by, bf16* lds) {
  const int tid = threadIdx.x;
  const int lane = tid & 63, g = lane >> 4, lm = lane & 15;
  const int wid = tid >> 6, wr = wid >> 1, wc = wid & 1;  // 4M x 2N waves, 64x64 each
  const long brow = (long)by * 256, bcol = (long)bx * 128;

  char* L = (char*)lds;
  // staging: A rows 0-127 at slot tid, rows 128-255 at +8192 (same k-group:
  // (row+128)>>1 & 3 == row>>1 & 3); B rows 0-127 at +16384.
  const int rowA = tid >> 2;
  const int kg = (tid & 3) ^ ((rowA >> 1) & 3);  // source pre-swizzle
  const bf16* aS = A + (brow + rowA) * (long)K + kg * 8;
  const bf16* bS = Bt + (bcol + rowA) * (long)K + kg * 8;
  const long aOff1 = 128l * K;
  const int dA = tid * 16;

#define STAGEB(t_) {                                                     \
    const int _b = (t_) % 3; const long _ko = (long)(t_) * 32;           \
    gload16(aS + _ko,         L + _b * 24576 + dA);                      \
    gload16(aS + aOff1 + _ko, L + _b * 24576 + 8192 + dA);               \
    gload16(bS + _ko,         L + _b * 24576 + 16384 + dA); }

  f32x4 zero = {0.f, 0.f, 0.f, 0.f};
  f32x4 acc[4][4];
#pragma unroll
  for (int i = 0; i < 4; ++i)
#pragma unroll
    for (int j = 0; j < 4; ++j) acc[i][j] = zero;

  STAGEB(0);
  STAGEB(1);

  const int nt = K >> 5;
  for (int t = 0; t < nt; ++t) {
    if (t + 2 < nt)       { STAGEB(t + 2); wait_vm6(); }  // certify tile t
    else if (t + 2 == nt) wait_vm3();
    else                  wait_vm0();
    barrier_raw();  // all waves' tile-t loads landed

    const char* Bf = L + (t % 3) * 24576;
    short8 aR[4], bR[4];
#pragma unroll
    for (int mi = 0; mi < 4; ++mi) {
      const int r = wr * 64 + mi * 16 + lm;
      aR[mi] = *reinterpret_cast<const short8*>(
          Bf + r * 64 + ((g ^ ((r >> 1) & 3)) << 4));
    }
#pragma unroll
    for (int ni = 0; ni < 4; ++ni) {
      const int r = wc * 64 + ni * 16 + lm;
      bR[ni] = *reinterpret_cast<const short8*>(
          Bf + 16384 + r * 64 + ((g ^ ((r >> 1) & 3)) << 4));
    }
    __builtin_amdgcn_s_setprio(1);
#pragma unroll
    for (int mi = 0; mi < 4; ++mi)
#pragma unroll
      for (int ni = 0; ni < 4; ++ni)
        acc[mi][ni] = __builtin_amdgcn_mfma_f32_16x16x32_bf16(aR[mi], bR[ni], acc[mi][ni], 0, 0, 0);
    __builtin_amdgcn_s_setprio(0);
    barrier_raw();  // buf (t)%3 free for staging at iter t+1
  }
#undef STAGEB

  // epilogue: D layout col = lane&15, row = (lane>>4)*4 + r
#pragma unroll
  for (int ni = 0; ni < 4; ++ni) {
    long n = bcol + wc * 64 + ni * 16 + lm;
    float bv = bias ? bias[n] : 0.f;
#pragma unroll
    for (int mi = 0; mi < 4; ++mi) {
      long m0 = brow + wr * 64 + mi * 16 + g * 4;
      if (Cvt) {  // V-proj: write vT [b][n][s], 4 consecutive s per lane
        long b = m0 >> 10, s0 = m0 & 1023;
        alignas(8) bf16 t4[4];
#pragma unroll
        for (int r = 0; r < 4; ++r) t4[r] = __float2bfloat16(acc[mi][ni][r] + bv);
        *reinterpret_cast<ushort4*>(Cvt + ((b << 10) + n) * 1024 + s0) =
            *reinterpret_cast<const ushort4*>(t4);
      } else {
#pragma unroll
        for (int r = 0; r < 4; ++r)
          Cb[(m0 + r) * 1024 + n] = __float2bfloat16(acc[mi][ni][r] + bv);
      }
    }
  }
}

// QKV fused, balanced: K 128 blocks (nt=128), V 128 (nt=128), Q 256 (nt=32).
// Heavy blocks first: round-robin dispatch pairs each CU with ~1 heavy + 1 Q
// -> uniform ~160 K-steps per CU.
__global__ __launch_bounds__(512, 4) void gemm_qkv_bal(
    const bf16* __restrict__ Ak, const bf16* __restrict__ Bk, const float* __restrict__ bk_, bf16* __restrict__ Ck, int Kk, int nbk,
    const bf16* __restrict__ Av, const bf16* __restrict__ Bv_, const float* __restrict__ bv_, bf16* __restrict__ CvT, int Kv, int nbv,
    const bf16* __restrict__ Aq, const bf16* __restrict__ Bq_, const float* __restrict__ bq_, bf16* __restrict__ Cq, int Kq) {
  __shared__ bf16 lds[36864];  // 72 KB
  int bid = blockIdx.x;
  const bf16 *A, *Bt; const float* bias; bf16 *C = nullptr, *Cvt = nullptr; int K, l, nb;
  if (bid < nbk)            { A = Ak; Bt = Bk;  bias = bk_; C = Ck;    K = Kk; l = bid;             nb = nbk; }
  else if (bid < nbk + nbv) { A = Av; Bt = Bv_; bias = bv_; Cvt = CvT; K = Kv; l = bid - nbk;       nb = nbv; }
  else                      { A = Aq; Bt = Bq_; bias = bq_; C = Cq;   K = Kq; l = bid - nbk - nbv; nb = gridDim.x - nbk - nbv; }
  // per-segment XCD swizzle (segment sizes and offsets are multiples of 8)
  int g = (l & 7) * (nb >> 3) + (l >> 3);
  gemm_bal_core(A, Bt, bias, C, Cvt, K, g & 7, g >> 3, lds);
}

// ---------------- 128^2 GEMM (2-phase dbuf, counted vmcnt) for O-proj ----------
__device__ __forceinline__ void gemm_core(const bf16* __restrict__ A, const bf16* __restrict__ Bt,
                                          const float* __restrict__ bias,
                                          bf16* __restrict__ Cb, float* __restrict__ Cf,
                                          int N, int K, int bx, int by,
                                          bf16* As, bf16* Bs) {
  const int tid = threadIdx.x;
  const int lane = tid & 63, g = lane >> 4, lm = lane & 15;
  const int wid = tid >> 6, wr = wid >> 1, wc = wid & 1;
  const long brow = (long)by * 128, bcol = (long)bx * 128;

  const bf16* asrc[4];
  const bf16* bsrc[4];
  int dsto[4];
#pragma unroll
  for (int t = 0; t < 4; ++t) {
    int sl = tid + t * 256;
    int row = sl >> 3;
    int kg = (sl & 7) ^ (row & 7);  // source pre-swizzle
    asrc[t] = A + (brow + row) * (long)K + kg * 8;
    bsrc[t] = Bt + (bcol + row) * (long)K + kg * 8;
    dsto[t] = sl * 16;
  }

  f32x4 zero = {0.f, 0.f, 0.f, 0.f};
  f32x4 acc[4][4];
#pragma unroll
  for (int i = 0; i < 4; ++i)
#pragma unroll
    for (int j = 0; j < 4; ++j) acc[i][j] = zero;

  char* Asc = (char*)As;
  char* Bsc = (char*)Bs;

#pragma unroll
  for (int t = 0; t < 4; ++t) {
    gload16(asrc[t], Asc + dsto[t]);
    gload16(bsrc[t], Bsc + dsto[t]);
    asrc[t] += 64; bsrc[t] += 64;
  }

  const int nt = K >> 6;
  for (int i = 0; i < nt; ++i) {
    const int cur = i & 1;
    if (i + 1 < nt) {
      const int nxt = cur ^ 1;
#pragma unroll
      for (int t = 0; t < 4; ++t) {
        gload16(asrc[t], Asc + nxt * 16384 + dsto[t]);
        gload16(bsrc[t], Bsc + nxt * 16384 + dsto[t]);
        asrc[t] += 64; bsrc[t] += 64;
      }
      wait_vm8();
    } else {
      wait_vm0();
    }
    barrier_raw();

    const char* Ab = Asc + cur * 16384;
    const char* Bb = Bsc + cur * 16384;
    __builtin_amdgcn_s_setprio(1);
#pragma unroll
    for (int ks = 0; ks < 2; ++ks) {
      short8 af[4], bfv[4];
#pragma unroll
      for (int mi = 0; mi < 4; ++mi) {
        int m = wr * 64 + mi * 16 + lm;
        af[mi] = *reinterpret_cast<const short8*>(
            Ab + ((m * 128 + ks * 64 + g * 16) ^ ((m & 7) << 4)));
      }
#pragma unroll
      for (int ni = 0; ni < 4; ++ni) {
        int n = wc * 64 + ni * 16 + lm;
        bfv[ni] = *reinterpret_cast<const short8*>(
            Bb + ((n * 128 + ks * 64 + g * 16) ^ ((n & 7) << 4)));
      }
#pragma unroll
      for (int mi = 0; mi < 4; ++mi)
#pragma unroll
        for (int ni = 0; ni < 4; ++ni)
          acc[mi][ni] = __builtin_amdgcn_mfma_f32_16x16x32_bf16(af[mi], bfv[ni], acc[mi][ni], 0, 0, 0);
    }
    __builtin_amdgcn_s_setprio(0);
    barrier_raw();
  }

#pragma unroll
  for (int ni = 0; ni < 4; ++ni) {
    long n = bcol + wc * 64 + ni * 16 + lm;
    float bv = bias ? bias[n] : 0.f;
#pragma unroll
    for (int mi = 0; mi < 4; ++mi) {
      long m0 = brow + wr * 64 + mi * 16 + g * 4;
#pragma unroll
      for (int r = 0; r < 4; ++r) {
        float o = acc[mi][ni][r] + bv;
        if (Cb) Cb[(m0 + r) * N + n] = __float2bfloat16(o);
        else    Cf[(m0 + r) * N + n] = o;
      }
    }
  }
}

__global__ __launch_bounds__(256) void gemm_bt(const bf16* __restrict__ A,
                                               const bf16* __restrict__ Bt,
                                               const float* __restrict__ bias,
                                               bf16* __restrict__ Cb,
                                               float* __restrict__ Cf,
                                               int N, int K) {
  __shared__ bf16 As[2 * 128 * 64];
  __shared__ bf16 Bs[2 * 128 * 64];
  int bid = blockIdx.x;
  int g = (bid & 7) * (gridDim.x >> 3) + (bid >> 3);
  gemm_core(A, Bt, bias, Cb, Cf, N, K, g & 7, g >> 3, As, Bs);
}

// ---------------- fused flash attention (2-phase, counted vmcnt, XCD swizzle) ----
__global__ __launch_bounds__(256) void attn_fused(const bf16* __restrict__ q,
                                                  const bf16* __restrict__ k,
                                                  const bf16* __restrict__ vT,
                                                  bf16* __restrict__ o) {
  constexpr float C2 = 0.18033688011112042f;  // (1/8) * log2(e)
  constexpr float THR = 6.0f;
  __shared__ bf16 Kl[2][64 * 64];
  __shared__ bf16 Vl[2][64 * 64];
  __shared__ bf16 Pl[4][16 * 64];
  const int tid = threadIdx.x;
  const int lane = tid & 63, g = lane >> 4, lm = lane & 15;
  const int wid = tid >> 6;
  int bid = blockIdx.x;
  int gl = (bid & 7) * 256 + (bid >> 3);
  const int qt = gl & 31, bh = gl >> 5;
  const int b = bh >> 4, h = bh & 15;
  const int qbase = qt * 64 + wid * 16;

  const bf16* qrow = q + (long)(b * Lc + qbase + lm) * DModel + h * 64;
  short8 qa0 = *reinterpret_cast<const short8*>(qrow + g * 8);
  short8 qa1 = *reinterpret_cast<const short8*>(qrow + 32 + g * 8);
#pragma unroll
  for (int j = 0; j < 8; ++j) {
    union { ushort u; bf16 h; } cv;
    cv.u = (ushort)qa0[j];
    bf16 s0 = __float2bfloat16(__bfloat162float(cv.h) * C2);
    qa0[j] = (short)*reinterpret_cast<ushort*>(&s0);
    cv.u = (ushort)qa1[j];
    bf16 s1 = __float2bfloat16(__bfloat162float(cv.h) * C2);
    qa1[j] = (short)*reinterpret_cast<ushort*>(&s1);
  }

  const bf16* kbase = k + (long)b * Sc * DModel + h * 64;
  const bf16* vbase = vT + ((long)b * DModel + h * 64) * Sc;

  const bf16* ksrc[2];
  const bf16* vsrc[2];
  int dsto[2];
#pragma unroll
  for (int t = 0; t < 2; ++t) {
    int sl = tid + t * 256;
    int row = sl >> 3;
    int cg = (sl & 7) ^ (row & 7);
    ksrc[t] = kbase + (long)row * DModel + cg * 8;
    vsrc[t] = vbase + (long)row * Sc + cg * 8;
    dsto[t] = sl * 16;
  }

  f32x4 zero = {0.f, 0.f, 0.f, 0.f};
  f32x4 accO[4];
#pragma unroll
  for (int i = 0; i < 4; ++i) accO[i] = zero;
  f32x4 accL = zero;
  float mst[4] = {-1e30f, -1e30f, -1e30f, -1e30f};

  short8 vones;
#pragma unroll
  for (int j = 0; j < 8; ++j) vones[j] = (short)0x3F80;  // bf16 1.0

  char* Klc = (char*)Kl;
  char* Vlc = (char*)Vl;
  char* Plc = (char*)Pl + wid * (16 * 64 * 2);

#pragma unroll
  for (int t = 0; t < 2; ++t) {
    gload16(ksrc[t], Klc + dsto[t]);
    gload16(vsrc[t], Vlc + dsto[t]);
    ksrc[t] += 64 * DModel; vsrc[t] += 64;
  }

  for (int j = 0; j < Sc / 64; ++j) {
    const int cur = j & 1;
    if (j + 1 < Sc / 64) {
      const int nxt = cur ^ 1;
#pragma unroll
      for (int t = 0; t < 2; ++t) {
        gload16(ksrc[t], Klc + nxt * 8192 + dsto[t]);
        gload16(vsrc[t], Vlc + nxt * 8192 + dsto[t]);
        ksrc[t] += 64 * DModel; vsrc[t] += 64;
      }
      wait_vm4();
    } else {
      wait_vm0();
    }
    barrier_raw();

    const char* Kb = Klc + cur * 8192;
    const char* Vb = Vlc + cur * 8192;

    f32x4 scv[4];
    __builtin_amdgcn_s_setprio(1);
#pragma unroll
    for (int st = 0; st < 4; ++st) {
      int s = st * 16 + lm;
      int sw = (s & 7) << 4;
      short8 kb0 = *reinterpret_cast<const short8*>(Kb + ((s * 128 + g * 16) ^ sw));
      short8 kb1 = *reinterpret_cast<const short8*>(Kb + ((s * 128 + 64 + g * 16) ^ sw));
      f32x4 z = zero;
      z = __builtin_amdgcn_mfma_f32_16x16x32_bf16(qa0, kb0, z, 0, 0, 0);
      z = __builtin_amdgcn_mfma_f32_16x16x32_bf16(qa1, kb1, z, 0, 0, 0);
      scv[st] = z;
    }
    __builtin_amdgcn_s_setprio(0);

    float pmax[4];
#pragma unroll
    for (int r = 0; r < 4; ++r)
      pmax[r] = fmaxf(fmaxf(scv[0][r], scv[1][r]), fmaxf(scv[2][r], scv[3][r]));
    int need = 0;
#pragma unroll
    for (int r = 0; r < 4; ++r) need |= (pmax[r] > mst[r] + THR) ? 1 : 0;
    if (__any(need)) {
#pragma unroll
      for (int r = 0; r < 4; ++r) {
        float mx = pmax[r];
        mx = fmaxf(mx, __shfl_xor(mx, 1));
        mx = fmaxf(mx, __shfl_xor(mx, 2));
        mx = fmaxf(mx, __shfl_xor(mx, 4));
        mx = fmaxf(mx, __shfl_xor(mx, 8));
        float mnew = fmaxf(mst[r], mx);
        float corr = __builtin_amdgcn_exp2f(mst[r] - mnew);
        mst[r] = mnew;
        accL[r] *= corr;
#pragma unroll
        for (int et = 0; et < 4; ++et) accO[et][r] *= corr;
      }
    }
#pragma unroll
    for (int r = 0; r < 4; ++r) {
      int qq = g * 4 + r;
      int swp = (qq & 7) << 4;
#pragma unroll
      for (int st = 0; st < 4; ++st) {
        float p = __builtin_amdgcn_exp2f(scv[st][r] - mst[r]);
        *reinterpret_cast<bf16*>(Plc + ((qq * 128 + (st * 16 + lm) * 2) ^ swp)) =
            __float2bfloat16(p);
      }
    }

    __builtin_amdgcn_s_setprio(1);
#pragma unroll
    for (int sk = 0; sk < 2; ++sk) {
      short8 pa = *reinterpret_cast<const short8*>(
          Plc + ((lm * 128 + sk * 64 + g * 16) ^ ((lm & 7) << 4)));
      accL = __builtin_amdgcn_mfma_f32_16x16x32_bf16(pa, vones, accL, 0, 0, 0);
#pragma unroll
      for (int et = 0; et < 4; ++et) {
        int e = et * 16 + lm;
        short8 vb = *reinterpret_cast<const short8*>(
            Vb + ((e * 128 + sk * 64 + g * 16) ^ ((e & 7) << 4)));
        accO[et] = __builtin_amdgcn_mfma_f32_16x16x32_bf16(pa, vb, accO[et], 0, 0, 0);
      }
    }
    __builtin_amdgcn_s_setprio(0);
    barrier_raw();
  }

#pragma unroll
  for (int r = 0; r < 4; ++r) {
    float inv = 1.0f / accL[r];
    long row = (long)(b * Lc + qbase + g * 4 + r);
#pragma unroll
    for (int et = 0; et < 4; ++et)
      o[row * DModel + h * 64 + et * 16 + lm] = __float2bfloat16(accO[et][r] * inv);
  }
}

// ---------------- host launch ----------------
extern "C" void kernel_launch(void* const* d_in, const int* in_sizes, int n_in,
                              void* d_out, int out_size, void* d_ws, size_t ws_size,
                              hipStream_t stream) {
  const float* tgt = (const float*)d_in[0];
  const float* src = (const float*)d_in[1];
  const float* val = (const float*)d_in[2];
  const float* Wq  = (const float*)d_in[3];
  const float* bq  = (const float*)d_in[4];
  const float* Wk  = (const float*)d_in[5];
  const float* bk  = (const float*)d_in[6];
  const float* Wv  = (const float*)d_in[7];
  const float* bv  = (const float*)d_in[8];
  const float* Wo  = (const float*)d_in[9];
  const float* bo  = (const float*)d_in[10];
  float* out = (float*)d_out;
  char* ws = (char*)d_ws;

  const long n4_tgt = (long)8192 * 1024 / 4;
  const long n4_sv  = (long)4096 * 4096 / 4;

  if (ws_size < (132ul << 20)) return;

  bf16* WqT  = (bf16*)(ws + (0l   << 20));  // 2 MB
  bf16* WkT  = (bf16*)(ws + (2l   << 20));  // 8 MB
  bf16* WvT  = (bf16*)(ws + (10l  << 20));  // 8 MB
  bf16* WoT  = (bf16*)(ws + (18l  << 20));  // 2 MB
  bf16* tgtb = (bf16*)(ws + (20l  << 20));  // 16 MB (attn out aliases later)
  bf16* srcb = (bf16*)(ws + (36l  << 20));  // 32 MB
  bf16* valb = (bf16*)(ws + (68l  << 20));  // 32 MB
  bf16* qb   = (bf16*)(ws + (100l << 20));  // 16 MB
  bf16* kb   = (bf16*)(ws + (116l << 20));  // 8 MB
  bf16* vTb  = (bf16*)(ws + (124l << 20));  // 8 MB [4][1024][1024] -> 132 MB
  bf16* attnb = tgtb;  // tgtb dead after QKV gemm

  transpose_cvt_w<<<10240, 256, 0, stream>>>(Wq, WqT, Wk, WkT, Wv, WvT, Wo, WoT);
  cvt3<<<4096, 256, 0, stream>>>(tgt, tgtb, n4_tgt, src, srcb, n4_sv, val, valb, n4_sv);
  // balanced grid: K 128 (nt=128) + V 128 (nt=128) + Q 256 (nt=32) = 512 = 2/CU
  gemm_qkv_bal<<<512, 512, 0, stream>>>(srcb, WkT, bk, kb, 4096, 128,
                                        valb, WvT, bv, vTb, 4096, 128,
                                        tgtb, WqT, bq, qb, 1024);
  attn_fused<<<2048, 256, 0, stream>>>(qb, kb, vTb, attnb);
  gemm_bt<<<512, 256, 0, stream>>>(attnb, WoT, bo, (bf16*)nullptr, out, 1024, 1024);
}